// Round 7
// baseline (278.532 us; speedup 1.0000x reference)
//
#include <hip/hip_runtime.h>
#include <hip/hip_bf16.h>
#include <stdint.h>

#define BATCH 16384
#define D 1024
#define NCLS 1000
#define NPROTO 5000
#define NPROTO_PAD 5120
#define BM 256
#define BN 128
#define BK 32
#define NKT 32
#define NBLK ((NPROTO_PAD / BN) * (BATCH / BM))   // 40 * 64 = 2560

typedef float f32x4 __attribute__((ext_vector_type(4)));
typedef __bf16 bf16x8 __attribute__((ext_vector_type(8)));

__device__ __forceinline__ unsigned short f2bf(float x) {
    unsigned u = __float_as_uint(x);
    u += 0x7FFFu + ((u >> 16) & 1u);   // RNE
    return (unsigned short)(u >> 16);
}
__device__ __forceinline__ unsigned enc_f32(float f) {
    unsigned u = __float_as_uint(f);
    return (u & 0x80000000u) ? ~u : (u | 0x80000000u);
}
__device__ __forceinline__ float dec_f32(unsigned e) {
    return __uint_as_float((e & 0x80000000u) ? (e ^ 0x80000000u) : ~e);
}

// ---------- normalize rows of z and P to bf16 (K-tiled, BK=32) ----------
// zbt[kt][BATCH][32], pbh[kt][NPROTO_PAD][32]: each 256x32 / 128x32 staging
// unit is globally contiguous.
__global__ __launch_bounds__(256) void k_prep(
        const float* __restrict__ z, const float* __restrict__ P,
        unsigned short* __restrict__ zbt, unsigned short* __restrict__ pbh,
        unsigned* __restrict__ posU, unsigned* __restrict__ negU) {
    const int b = blockIdx.x;
    const int t = threadIdx.x;
    if (b < BATCH && t == 0) {
        posU[b] = enc_f32(-INFINITY);
        negU[b] = enc_f32(-INFINITY);
    }
    const int kt = t >> 3;            // (4t)>>5
    const int off = (4 * t) & 31;
    const float* src = nullptr;
    unsigned short* dst;
    if (b < BATCH) {
        src = z + (size_t)b * D;
        dst = zbt + ((size_t)kt * BATCH + b) * 32 + off;
    } else {
        const int r = b - BATCH;
        dst = pbh + ((size_t)kt * NPROTO_PAD + r) * 32 + off;
        if (r < NPROTO) src = P + (size_t)r * D;
    }
    if (src == nullptr) {
        *(ushort4*)dst = make_ushort4(0, 0, 0, 0);
        return;
    }
    float4 v = ((const float4*)src)[t];
    float ss = v.x * v.x + v.y * v.y + v.z * v.z + v.w * v.w;
    #pragma unroll
    for (int o = 32; o >= 1; o >>= 1) ss += __shfl_xor(ss, o);
    __shared__ float red[4];
    const int wave = t >> 6;
    if ((t & 63) == 0) red[wave] = ss;
    __syncthreads();
    const float s = red[0] + red[1] + red[2] + red[3];
    const float inv = 1.0f / fmaxf(sqrtf(s), 1e-12f);
    ushort4 o4;
    o4.x = f2bf(v.x * inv); o4.y = f2bf(v.y * inv);
    o4.z = f2bf(v.z * inv); o4.w = f2bf(v.w * inv);
    *(ushort4*)dst = o4;
}

// async global->LDS, 16B per lane, dest = wave-uniform base + lane*16
#define GLL(gp, lp) __builtin_amdgcn_global_load_lds( \
    (__attribute__((address_space(1))) const unsigned int*)(const void*)(gp), \
    (__attribute__((address_space(3))) unsigned int*)(void*)(lp), 16, 0, 0)

#define MM(A, B, C) __builtin_amdgcn_mfma_f32_16x16x32_bf16(A, B, C, 0, 0, 0)

// ---------- 256x128 bf16 GEMM, 2 independent blocks/CU, 3-deep ring ----
// TLP experiment: 256-thread blocks (4 waves, 72KB LDS) so two blocks
// co-reside per CU with independent barrier domains.
// Swizzle involution byte^=((byte>>7)&3)<<4 on GLL source and ds_read.
__global__ __launch_bounds__(256, 2) void k_gemm(
        const unsigned short* __restrict__ zbt,
        const unsigned short* __restrict__ pbh,
        const int* __restrict__ y,
        unsigned* __restrict__ posU, unsigned* __restrict__ negU) {
    __shared__ __align__(16) unsigned short LA[3][256][32];   // 48 KiB
    __shared__ __align__(16) unsigned short LB[3][128][32];   // 24 KiB

    const int t = threadIdx.x;
    const int w = t >> 6, lane = t & 63;
    const int lm = lane & 15, lk = lane >> 4;
    const int wm = w >> 1, wn = w & 1;       // 2(M) x 2(N) wave grid

    // XCD decode: xcd owns 8 row-panels (4MB A = its L2); 8 consecutive
    // blocks within an xcd share one B col-panel.
    const int bid = blockIdx.x;
    const int xcd = bid & 7;
    const int idx = bid >> 3;                // 0..319
    const int yy = xcd * 8 + (idx & 7);      // row-tile 0..63
    const int cc = idx >> 3;                 // col-tile 0..39
    const int rowbase = yy * BM;
    const int colbase = cc * BN;

    // staging source swizzle: (lane*16 ^ X) with X from lane bits 3-4
    const int X = ((lane >> 3) & 3) << 4;
    const int lsw = ((lane * 16) ^ X) >> 1;          // element offset

    // ds_read swizzled k-slot (bytes)
    const int ksl = ((lk ^ ((lm >> 1) & 3)) << 4);
    const int aoff = (wm * 64 + lm) * 64 + ksl;      // byte off in LA[s]
    const int boff = (wn * 64 + lm) * 64 + ksl;      // byte off in LB[s]

#define STG_A(T, S) do {                                                     \
    const unsigned short* sA_ = zbt + ((size_t)(T) * BATCH + rowbase) * 32;  \
    unsigned short* dA_ = &LA[S][0][0] + w * 2048;                           \
    GLL(sA_ + w * 2048 + 0    + lsw, dA_ + 0);                               \
    GLL(sA_ + w * 2048 + 512  + lsw, dA_ + 512);                             \
    GLL(sA_ + w * 2048 + 1024 + lsw, dA_ + 1024);                            \
    GLL(sA_ + w * 2048 + 1536 + lsw, dA_ + 1536);                            \
} while (0)
#define STG_B(T, S) do {                                                     \
    const unsigned short* sB_ = pbh + ((size_t)(T) * NPROTO_PAD + colbase) * 32; \
    unsigned short* dB_ = &LB[S][0][0] + w * 1024;                           \
    GLL(sB_ + w * 1024 + 0   + lsw, dB_ + 0);                                \
    GLL(sB_ + w * 1024 + 512 + lsw, dB_ + 512);                              \
} while (0)

#define WV6 asm volatile("s_waitcnt vmcnt(6)" ::: "memory")
#define WV0 asm volatile("s_waitcnt vmcnt(0)" ::: "memory")
#define NOV ((void)0)
#define NOS ((void)0)

    f32x4 acc[8][4];
    #pragma unroll
    for (int i = 0; i < 8; ++i)
        #pragma unroll
        for (int j = 0; j < 4; ++j) {
            f32x4 z4 = {0.0f, 0.0f, 0.0f, 0.0f};
            acc[i][j] = z4;
        }

    bf16x8 b0_, b1_, b2_, b3_;

// phase: 4 A-frag reads (+4 B on RB) -> stage -> barrier -> lgkm0 ->
// 16 MFMA -> [wait] -> barrier
#define PH(SLOT, MH, RB, STG, WAIT) do {                                 \
    const char* lab_ = (const char*)&LA[SLOT][0][0];                     \
    const bf16x8 a0_ = *(const bf16x8*)(lab_ + aoff + (MH)*8192 + 0);    \
    const bf16x8 a1_ = *(const bf16x8*)(lab_ + aoff + (MH)*8192 + 1024); \
    const bf16x8 a2_ = *(const bf16x8*)(lab_ + aoff + (MH)*8192 + 2048); \
    const bf16x8 a3_ = *(const bf16x8*)(lab_ + aoff + (MH)*8192 + 3072); \
    if (RB) {                                                            \
        const char* lbb_ = (const char*)&LB[SLOT][0][0];                 \
        b0_ = *(const bf16x8*)(lbb_ + boff + 0);                         \
        b1_ = *(const bf16x8*)(lbb_ + boff + 1024);                      \
        b2_ = *(const bf16x8*)(lbb_ + boff + 2048);                      \
        b3_ = *(const bf16x8*)(lbb_ + boff + 3072);                      \
    }                                                                    \
    STG;                                                                 \
    asm volatile("s_barrier" ::: "memory");                              \
    asm volatile("s_waitcnt lgkmcnt(0)" ::: "memory");                   \
    __builtin_amdgcn_s_setprio(1);                                       \
    acc[4 * (MH) + 0][0] = MM(a0_, b0_, acc[4 * (MH) + 0][0]);           \
    acc[4 * (MH) + 0][1] = MM(a0_, b1_, acc[4 * (MH) + 0][1]);           \
    acc[4 * (MH) + 0][2] = MM(a0_, b2_, acc[4 * (MH) + 0][2]);           \
    acc[4 * (MH) + 0][3] = MM(a0_, b3_, acc[4 * (MH) + 0][3]);           \
    acc[4 * (MH) + 1][0] = MM(a1_, b0_, acc[4 * (MH) + 1][0]);           \
    acc[4 * (MH) + 1][1] = MM(a1_, b1_, acc[4 * (MH) + 1][1]);           \
    acc[4 * (MH) + 1][2] = MM(a1_, b2_, acc[4 * (MH) + 1][2]);           \
    acc[4 * (MH) + 1][3] = MM(a1_, b3_, acc[4 * (MH) + 1][3]);           \
    acc[4 * (MH) + 2][0] = MM(a2_, b0_, acc[4 * (MH) + 2][0]);           \
    acc[4 * (MH) + 2][1] = MM(a2_, b1_, acc[4 * (MH) + 2][1]);           \
    acc[4 * (MH) + 2][2] = MM(a2_, b2_, acc[4 * (MH) + 2][2]);           \
    acc[4 * (MH) + 2][3] = MM(a2_, b3_, acc[4 * (MH) + 2][3]);           \
    acc[4 * (MH) + 3][0] = MM(a3_, b0_, acc[4 * (MH) + 3][0]);           \
    acc[4 * (MH) + 3][1] = MM(a3_, b1_, acc[4 * (MH) + 3][1]);           \
    acc[4 * (MH) + 3][2] = MM(a3_, b2_, acc[4 * (MH) + 3][2]);           \
    acc[4 * (MH) + 3][3] = MM(a3_, b3_, acc[4 * (MH) + 3][3]);           \
    __builtin_amdgcn_s_setprio(0);                                       \
    WAIT;                                                                \
    asm volatile("s_barrier" ::: "memory");                              \
} while (0)

    // prologue: stage tiles 0 and 1 (slots 0,1), complete tile 0, barrier
    STG_A(0, 0); STG_B(0, 0);
    STG_A(1, 1); STG_B(1, 1);
    WV6;                            // completes A(0),B(0); leaves tile 1
    asm volatile("s_barrier" ::: "memory");

    // tile t (slot t%3): PH0 computes MH0 + stages A(t+2); PH1 computes
    // MH1 + stages B(t+2); single WV6 at end of PH1 completes A/B(t+1).
    int cs = 0, ss = 2;
    #pragma unroll 1
    for (int tt = 0; tt < NKT - 2; ++tt) {
        PH(cs, 0, 1, STG_A(tt + 2, ss), NOV);
        PH(cs, 1, 0, STG_B(tt + 2, ss), WV6);
        cs = (cs == 2) ? 0 : cs + 1;
        ss = (ss == 2) ? 0 : ss + 1;
    }
    // t=30: no stage; drain for tile 31
    PH(cs, 0, 1, NOS, NOV);
    PH(cs, 1, 0, NOS, WV0);
    cs = (cs == 2) ? 0 : cs + 1;
    // t=31: last tile
    PH(cs, 0, 1, NOS, NOV);
    PH(cs, 1, 0, NOS, NOV);

    // fused epilogue: masked pos/neg max per output row
    // C/D layout: col = lane&15 (proto), row = (lane>>4)*4 + reg (batch)
    const int col00 = colbase + wn * 64 + lm;
    #pragma unroll
    for (int mi = 0; mi < 8; ++mi) {
        #pragma unroll
        for (int r = 0; r < 4; ++r) {
            const int row_g = rowbase + (mi >> 2) * 128 + wm * 64 +
                              (mi & 3) * 16 + lk * 4 + r;
            const int yv = y[row_g];
            float pm = -INFINITY, nm = -INFINITY;
            #pragma unroll
            for (int ni = 0; ni < 4; ++ni) {
                const int col_g = col00 + ni * 16;
                const float v = acc[mi][ni][r];
                const bool same = (col_g / 5) == yv;
                if (same) pm = fmaxf(pm, v);
                else if (col_g < NPROTO) nm = fmaxf(nm, v);
            }
            #pragma unroll
            for (int off = 1; off < 16; off <<= 1) {
                pm = fmaxf(pm, __shfl_xor(pm, off));
                nm = fmaxf(nm, __shfl_xor(nm, off));
            }
            if (lm == 0) {
                if (pm > -INFINITY) atomicMax(&posU[row_g], enc_f32(pm));
                if (nm > -INFINITY) atomicMax(&negU[row_g], enc_f32(nm));
            }
        }
    }
#undef PH
#undef STG_A
#undef STG_B
}

// ---------- decode to output ----------
__global__ __launch_bounds__(256) void k_finish(
        const unsigned* __restrict__ posU, const unsigned* __restrict__ negU,
        float* __restrict__ out) {
    const int i = blockIdx.x * 256 + threadIdx.x;
    if (i < BATCH) {
        out[i] = dec_f32(posU[i]);
        out[BATCH + i] = dec_f32(negU[i]);
    }
}

extern "C" void kernel_launch(void* const* d_in, const int* in_sizes, int n_in,
                              void* d_out, int out_size, void* d_ws, size_t ws_size,
                              hipStream_t stream) {
    const float* z = (const float*)d_in[0];
    const int*   y = (const int*)d_in[1];
    const float* P = (const float*)d_in[2];

    // ws: zbt 33.5MB | pbh 10.5MB | posU 64KB | negU 64KB
    unsigned short* zbt = (unsigned short*)d_ws;
    unsigned short* pbh = zbt + (size_t)NKT * BATCH * 32;
    unsigned* posU = (unsigned*)(pbh + (size_t)NKT * NPROTO_PAD * 32);
    unsigned* negU = posU + BATCH;
    float* out = (float*)d_out;

    k_prep<<<BATCH + NPROTO_PAD, 256, 0, stream>>>(z, P, zbt, pbh, posU, negU);
    k_gemm<<<NBLK, 256, 0, stream>>>(zbt, pbh, y, posU, negU);
    k_finish<<<BATCH / 256, 256, 0, stream>>>(posU, negU, out);
}

// Round 8
// 266.961 us; speedup vs baseline: 1.0433x; 1.0433x over previous
//
#include <hip/hip_runtime.h>
#include <hip/hip_bf16.h>
#include <stdint.h>

#define BATCH 16384
#define D 1024
#define NCLS 1000
#define NPROTO 5000
#define NPROTO_PAD 5120
#define BM 64                 // rows per block (one block per CU)
#define NCH 20                // N chunks of 256 cols
#define NKT 32                // K tiles of 32
#define KSTRIDE (320 * 64 * 8)   // pbf elems per kt

typedef float f32x4 __attribute__((ext_vector_type(4)));
typedef __bf16 bf16x8 __attribute__((ext_vector_type(8)));

__device__ __forceinline__ unsigned short f2bf(float x) {
    unsigned u = __float_as_uint(x);
    u += 0x7FFFu + ((u >> 16) & 1u);   // RNE
    return (unsigned short)(u >> 16);
}

// ---------- normalize rows of z and P to bf16 ----------
// zb:  [BATCH][1024] row-major
// pbf: [kt 0..31][grp 0..319][lane 0..63][8]  (lane = (col&15) + 16*lk)
//      -> a wave's B-fragment load is contiguous 1KB
__global__ __launch_bounds__(256) void k_prep(
        const float* __restrict__ z, const float* __restrict__ P,
        unsigned short* __restrict__ zb, unsigned short* __restrict__ pbf) {
    const int b = blockIdx.x;
    const int t = threadIdx.x;
    const int e0 = 4 * t;
    const float* src = nullptr;
    unsigned short* dst;
    if (b < BATCH) {
        src = z + (size_t)b * D;
        dst = zb + (size_t)b * D + e0;
    } else {
        const int r = b - BATCH;
        const int kt = e0 >> 5;
        const int lk = (e0 >> 3) & 3;
        const int ke = e0 & 7;
        dst = pbf + (((size_t)kt * 320 + (r >> 4)) * 64 + (r & 15) + 16 * lk) * 8 + ke;
        if (r < NPROTO) src = P + (size_t)r * D;
    }
    if (src == nullptr) {                 // padded proto row -> zeros
        *(ushort4*)dst = make_ushort4(0, 0, 0, 0);
        return;
    }
    float4 v = ((const float4*)src)[t];
    float ss = v.x * v.x + v.y * v.y + v.z * v.z + v.w * v.w;
    #pragma unroll
    for (int o = 32; o >= 1; o >>= 1) ss += __shfl_xor(ss, o);
    __shared__ float red[4];
    const int wave = t >> 6;
    if ((t & 63) == 0) red[wave] = ss;
    __syncthreads();
    const float s = red[0] + red[1] + red[2] + red[3];
    const float inv = 1.0f / fmaxf(sqrtf(s), 1e-12f);
    ushort4 o4;
    o4.x = f2bf(v.x * inv); o4.y = f2bf(v.y * inv);
    o4.z = f2bf(v.z * inv); o4.w = f2bf(v.w * inv);
    *(ushort4*)dst = o4;
}

#define MM(A, B, C) __builtin_amdgcn_mfma_f32_16x16x32_bf16(A, B, C, 0, 0, 0)

// ---------- persistent-tile GEMM: A resident in LDS, B streamed to regs ----
// 256 blocks x 512 threads. No barriers / GLL / waitcnt-asm in the main loop.
__global__ __launch_bounds__(512, 2) void k_gemm(
        const unsigned short* __restrict__ zb,
        const unsigned short* __restrict__ pbf,
        const int* __restrict__ y,
        float* __restrict__ out) {
    // A fragment-packed: LA[kt][row-group 0..3][lane][8]
    __shared__ __align__(16) unsigned short LA[NKT][4][64][8];   // 128 KiB
    __shared__ float redP[8][64];
    __shared__ float redN[8][64];

    const int t = threadIdx.x;
    const int w = t >> 6;                // wave 0..7 = N-slice
    const int lane = t & 63;
    const int lm = lane & 15, lk = lane >> 4;
    const int rowbase = blockIdx.x * BM;

    // ---- one-time: stage this block's 64x1024 A tile, fragment-packed ----
    {
        const int ktw = lane >> 1;
        const int lk0 = (lane & 1) * 2;
        #pragma unroll
        for (int j = 0; j < 8; ++j) {
            const int r = w * 8 + j;
            const unsigned short* gp = zb + (size_t)(rowbase + r) * D + lane * 16;
            const bf16x8 v0 = *(const bf16x8*)gp;
            const bf16x8 v1 = *(const bf16x8*)(gp + 8);
            *(bf16x8*)&LA[ktw][r >> 4][(r & 15) + 16 * lk0][0] = v0;
            *(bf16x8*)&LA[ktw][r >> 4][(r & 15) + 16 * (lk0 + 1)][0] = v1;
        }
    }
    // this lane's 16 output rows' labels
    int yv[16];
    #pragma unroll
    for (int mi = 0; mi < 4; ++mi)
        #pragma unroll
        for (int r = 0; r < 4; ++r)
            yv[mi * 4 + r] = y[rowbase + mi * 16 + lk * 4 + r];

    __syncthreads();

    float pmv[16], nmv[16];
    #pragma unroll
    for (int i = 0; i < 16; ++i) { pmv[i] = -INFINITY; nmv[i] = -INFINITY; }

    // ---- N-chunk sweep: 20 chunks x 256 cols; wave w owns cols w*32..+32 --
    for (int c = 0; c < NCH; ++c) {
        const int grp0 = c * 16 + w * 2;
        const unsigned short* pB = pbf + ((size_t)grp0 * 64 + lane) * 8;

        f32x4 acc[4][2];
        #pragma unroll
        for (int mi = 0; mi < 4; ++mi)
            #pragma unroll
            for (int ni = 0; ni < 2; ++ni) {
                f32x4 z4 = {0.0f, 0.0f, 0.0f, 0.0f};
                acc[mi][ni] = z4;
            }

        // prologue: B frags for kt 0 and 1
        bf16x8 b00 = *(const bf16x8*)(pB);
        bf16x8 b01 = *(const bf16x8*)(pB + 512);
        bf16x8 b10 = *(const bf16x8*)(pB + KSTRIDE);
        bf16x8 b11 = *(const bf16x8*)(pB + KSTRIDE + 512);

        #pragma unroll 1
        for (int kt = 0; kt < NKT; kt += 2) {
            // even K-tile: consume b0x, prefetch kt+2
            {
                const bf16x8 a0 = *(const bf16x8*)&LA[kt][0][lane][0];
                const bf16x8 a1 = *(const bf16x8*)&LA[kt][1][lane][0];
                const bf16x8 a2 = *(const bf16x8*)&LA[kt][2][lane][0];
                const bf16x8 a3 = *(const bf16x8*)&LA[kt][3][lane][0];
                acc[0][0] = MM(a0, b00, acc[0][0]);
                acc[0][1] = MM(a0, b01, acc[0][1]);
                acc[1][0] = MM(a1, b00, acc[1][0]);
                acc[1][1] = MM(a1, b01, acc[1][1]);
                acc[2][0] = MM(a2, b00, acc[2][0]);
                acc[2][1] = MM(a2, b01, acc[2][1]);
                acc[3][0] = MM(a3, b00, acc[3][0]);
                acc[3][1] = MM(a3, b01, acc[3][1]);
                const int ktn = (kt + 2 < NKT) ? kt + 2 : NKT - 1;
                b00 = *(const bf16x8*)(pB + (size_t)ktn * KSTRIDE);
                b01 = *(const bf16x8*)(pB + (size_t)ktn * KSTRIDE + 512);
            }
            // odd K-tile: consume b1x, prefetch kt+3
            {
                const bf16x8 a0 = *(const bf16x8*)&LA[kt + 1][0][lane][0];
                const bf16x8 a1 = *(const bf16x8*)&LA[kt + 1][1][lane][0];
                const bf16x8 a2 = *(const bf16x8*)&LA[kt + 1][2][lane][0];
                const bf16x8 a3 = *(const bf16x8*)&LA[kt + 1][3][lane][0];
                acc[0][0] = MM(a0, b10, acc[0][0]);
                acc[0][1] = MM(a0, b11, acc[0][1]);
                acc[1][0] = MM(a1, b10, acc[1][0]);
                acc[1][1] = MM(a1, b11, acc[1][1]);
                acc[2][0] = MM(a2, b10, acc[2][0]);
                acc[2][1] = MM(a2, b11, acc[2][1]);
                acc[3][0] = MM(a3, b10, acc[3][0]);
                acc[3][1] = MM(a3, b11, acc[3][1]);
                const int ktn = (kt + 3 < NKT) ? kt + 3 : NKT - 1;
                b10 = *(const bf16x8*)(pB + (size_t)ktn * KSTRIDE);
                b11 = *(const bf16x8*)(pB + (size_t)ktn * KSTRIDE + 512);
            }
        }

        // merge chunk into running pos/neg maxes (register-only)
        #pragma unroll
        for (int ni = 0; ni < 2; ++ni) {
            const unsigned col = (unsigned)(c * 256 + w * 32 + ni * 16 + lm);
            const unsigned lbl = __umulhi(col, 0xCCCCCCCDu) >> 2;   // col/5
            const bool valid = col < NPROTO;
            #pragma unroll
            for (int mi = 0; mi < 4; ++mi)
                #pragma unroll
                for (int r = 0; r < 4; ++r) {
                    const float v = acc[mi][ni][r];
                    const bool same = (lbl == (unsigned)yv[mi * 4 + r]);
                    const int i = mi * 4 + r;
                    pmv[i] = same ? fmaxf(pmv[i], v) : pmv[i];
                    nmv[i] = (!same && valid) ? fmaxf(nmv[i], v) : nmv[i];
                }
        }
    }

    // reduce over the 16 col-lanes (lm) in-register
    #pragma unroll
    for (int i = 0; i < 16; ++i) {
        #pragma unroll
        for (int off = 1; off < 16; off <<= 1) {
            pmv[i] = fmaxf(pmv[i], __shfl_xor(pmv[i], off));
            nmv[i] = fmaxf(nmv[i], __shfl_xor(nmv[i], off));
        }
    }
    if (lm == 0) {
        #pragma unroll
        for (int mi = 0; mi < 4; ++mi)
            #pragma unroll
            for (int r = 0; r < 4; ++r) {
                redP[w][mi * 16 + lk * 4 + r] = pmv[mi * 4 + r];
                redN[w][mi * 16 + lk * 4 + r] = nmv[mi * 4 + r];
            }
    }
    __syncthreads();
    // final cross-wave merge + direct output write (no atomics)
    if (t < 64) {
        float p = redP[0][t], n = redN[0][t];
        #pragma unroll
        for (int ww = 1; ww < 8; ++ww) {
            p = fmaxf(p, redP[ww][t]);
            n = fmaxf(n, redN[ww][t]);
        }
        out[rowbase + t] = p;
        out[BATCH + rowbase + t] = n;
    }
}

extern "C" void kernel_launch(void* const* d_in, const int* in_sizes, int n_in,
                              void* d_out, int out_size, void* d_ws, size_t ws_size,
                              hipStream_t stream) {
    const float* z = (const float*)d_in[0];
    const int*   y = (const int*)d_in[1];
    const float* P = (const float*)d_in[2];

    // ws: zb 33.5MB | pbf 10.5MB
    unsigned short* zb = (unsigned short*)d_ws;
    unsigned short* pbf = zb + (size_t)BATCH * D;
    float* out = (float*)d_out;

    k_prep<<<BATCH + NPROTO_PAD, 256, 0, stream>>>(z, P, zb, pbf);
    k_gemm<<<BATCH / BM, 512, 0, stream>>>(zb, pbf, y, out);
}

// Round 9
// 188.395 us; speedup vs baseline: 1.4784x; 1.4170x over previous
//
#include <hip/hip_runtime.h>
#include <hip/hip_bf16.h>
#include <stdint.h>

#define BATCH 16384
#define D 1024
#define NCLS 1000
#define NPROTO 5000
#define NPROTO_PAD 5120
#define BM 64                 // rows per block (one block per CU)
#define NCH 10                // N chunks of 512 cols (16 waves x 32)
#define NKT 32                // K tiles of 32
#define KSTRIDE (320 * 64 * 8)   // pbf elems per kt

typedef float f32x4 __attribute__((ext_vector_type(4)));
typedef __bf16 bf16x8 __attribute__((ext_vector_type(8)));

__device__ __forceinline__ unsigned short f2bf(float x) {
    unsigned u = __float_as_uint(x);
    u += 0x7FFFu + ((u >> 16) & 1u);   // RNE
    return (unsigned short)(u >> 16);
}

// ---------- normalize rows of z and P to bf16 ----------
// zb:  [BATCH][1024] row-major
// pbf: [kt 0..31][grp 0..319][lane 0..63][8]  (lane = (col&15) + 16*lk)
//      -> a wave's B-fragment load is contiguous 1KB
__global__ __launch_bounds__(256) void k_prep(
        const float* __restrict__ z, const float* __restrict__ P,
        unsigned short* __restrict__ zb, unsigned short* __restrict__ pbf) {
    const int b = blockIdx.x;
    const int t = threadIdx.x;
    const int e0 = 4 * t;
    const float* src = nullptr;
    unsigned short* dst;
    if (b < BATCH) {
        src = z + (size_t)b * D;
        dst = zb + (size_t)b * D + e0;
    } else {
        const int r = b - BATCH;
        const int kt = e0 >> 5;
        const int lk = (e0 >> 3) & 3;
        const int ke = e0 & 7;
        dst = pbf + (((size_t)kt * 320 + (r >> 4)) * 64 + (r & 15) + 16 * lk) * 8 + ke;
        if (r < NPROTO) src = P + (size_t)r * D;
    }
    if (src == nullptr) {                 // padded proto row -> zeros
        *(ushort4*)dst = make_ushort4(0, 0, 0, 0);
        return;
    }
    float4 v = ((const float4*)src)[t];
    float ss = v.x * v.x + v.y * v.y + v.z * v.z + v.w * v.w;
    #pragma unroll
    for (int o = 32; o >= 1; o >>= 1) ss += __shfl_xor(ss, o);
    __shared__ float red[4];
    const int wave = t >> 6;
    if ((t & 63) == 0) red[wave] = ss;
    __syncthreads();
    const float s = red[0] + red[1] + red[2] + red[3];
    const float inv = 1.0f / fmaxf(sqrtf(s), 1e-12f);
    ushort4 o4;
    o4.x = f2bf(v.x * inv); o4.y = f2bf(v.y * inv);
    o4.z = f2bf(v.z * inv); o4.w = f2bf(v.w * inv);
    *(ushort4*)dst = o4;
}

#define MM(A, B, C) __builtin_amdgcn_mfma_f32_16x16x32_bf16(A, B, C, 0, 0, 0)

// ---------- persistent-tile GEMM: A resident in LDS, B streamed to regs ----
// 256 blocks x 1024 threads (16 waves = 4/SIMD). No barriers / GLL /
// waitcnt-asm in the main loop. Pure-TLP experiment vs R8 (8 waves).
__global__ __launch_bounds__(1024, 4) void k_gemm(
        const unsigned short* __restrict__ zb,
        const unsigned short* __restrict__ pbf,
        const int* __restrict__ y,
        float* __restrict__ out) {
    // A fragment-packed: LA[kt][row-group 0..3][lane][8]
    __shared__ __align__(16) unsigned short LA[NKT][4][64][8];   // 128 KiB
    __shared__ float redP[16][64];
    __shared__ float redN[16][64];

    const int t = threadIdx.x;
    const int w = t >> 6;                // wave 0..15 = N-slice
    const int lane = t & 63;
    const int lm = lane & 15, lk = lane >> 4;
    const int rowbase = blockIdx.x * BM;

    // ---- one-time: stage this block's 64x1024 A tile, fragment-packed ----
    {
        const int ktw = lane >> 1;
        const int lk0 = (lane & 1) * 2;
        #pragma unroll
        for (int j = 0; j < 4; ++j) {
            const int r = w * 4 + j;
            const unsigned short* gp = zb + (size_t)(rowbase + r) * D + lane * 16;
            const bf16x8 v0 = *(const bf16x8*)gp;
            const bf16x8 v1 = *(const bf16x8*)(gp + 8);
            *(bf16x8*)&LA[ktw][r >> 4][(r & 15) + 16 * lk0][0] = v0;
            *(bf16x8*)&LA[ktw][r >> 4][(r & 15) + 16 * (lk0 + 1)][0] = v1;
        }
    }
    // this lane's 16 output rows' labels
    int yv[16];
    #pragma unroll
    for (int mi = 0; mi < 4; ++mi)
        #pragma unroll
        for (int r = 0; r < 4; ++r)
            yv[mi * 4 + r] = y[rowbase + mi * 16 + lk * 4 + r];

    __syncthreads();

    float pmv[16], nmv[16];
    #pragma unroll
    for (int i = 0; i < 16; ++i) { pmv[i] = -INFINITY; nmv[i] = -INFINITY; }

    // ---- N-chunk sweep: 10 chunks x 512 cols; wave w owns cols w*32..+32 --
    for (int c = 0; c < NCH; ++c) {
        const int grp0 = c * 32 + w * 2;
        const unsigned short* pB = pbf + ((size_t)grp0 * 64 + lane) * 8;

        f32x4 acc[4][2];
        #pragma unroll
        for (int mi = 0; mi < 4; ++mi)
            #pragma unroll
            for (int ni = 0; ni < 2; ++ni) {
                f32x4 z4 = {0.0f, 0.0f, 0.0f, 0.0f};
                acc[mi][ni] = z4;
            }

        // prologue: B frags for kt 0 and 1
        bf16x8 b00 = *(const bf16x8*)(pB);
        bf16x8 b01 = *(const bf16x8*)(pB + 512);
        bf16x8 b10 = *(const bf16x8*)(pB + KSTRIDE);
        bf16x8 b11 = *(const bf16x8*)(pB + KSTRIDE + 512);

        #pragma unroll 1
        for (int kt = 0; kt < NKT; kt += 2) {
            // even K-tile: consume b0x, prefetch kt+2
            {
                const bf16x8 a0 = *(const bf16x8*)&LA[kt][0][lane][0];
                const bf16x8 a1 = *(const bf16x8*)&LA[kt][1][lane][0];
                const bf16x8 a2 = *(const bf16x8*)&LA[kt][2][lane][0];
                const bf16x8 a3 = *(const bf16x8*)&LA[kt][3][lane][0];
                acc[0][0] = MM(a0, b00, acc[0][0]);
                acc[0][1] = MM(a0, b01, acc[0][1]);
                acc[1][0] = MM(a1, b00, acc[1][0]);
                acc[1][1] = MM(a1, b01, acc[1][1]);
                acc[2][0] = MM(a2, b00, acc[2][0]);
                acc[2][1] = MM(a2, b01, acc[2][1]);
                acc[3][0] = MM(a3, b00, acc[3][0]);
                acc[3][1] = MM(a3, b01, acc[3][1]);
                const int ktn = (kt + 2 < NKT) ? kt + 2 : NKT - 1;
                b00 = *(const bf16x8*)(pB + (size_t)ktn * KSTRIDE);
                b01 = *(const bf16x8*)(pB + (size_t)ktn * KSTRIDE + 512);
            }
            // odd K-tile: consume b1x, prefetch kt+3
            {
                const bf16x8 a0 = *(const bf16x8*)&LA[kt + 1][0][lane][0];
                const bf16x8 a1 = *(const bf16x8*)&LA[kt + 1][1][lane][0];
                const bf16x8 a2 = *(const bf16x8*)&LA[kt + 1][2][lane][0];
                const bf16x8 a3 = *(const bf16x8*)&LA[kt + 1][3][lane][0];
                acc[0][0] = MM(a0, b10, acc[0][0]);
                acc[0][1] = MM(a0, b11, acc[0][1]);
                acc[1][0] = MM(a1, b10, acc[1][0]);
                acc[1][1] = MM(a1, b11, acc[1][1]);
                acc[2][0] = MM(a2, b10, acc[2][0]);
                acc[2][1] = MM(a2, b11, acc[2][1]);
                acc[3][0] = MM(a3, b10, acc[3][0]);
                acc[3][1] = MM(a3, b11, acc[3][1]);
                const int ktn = (kt + 3 < NKT) ? kt + 3 : NKT - 1;
                b10 = *(const bf16x8*)(pB + (size_t)ktn * KSTRIDE);
                b11 = *(const bf16x8*)(pB + (size_t)ktn * KSTRIDE + 512);
            }
        }

        // merge chunk into running pos/neg maxes (register-only)
        #pragma unroll
        for (int ni = 0; ni < 2; ++ni) {
            const unsigned col = (unsigned)(c * 512 + w * 32 + ni * 16 + lm);
            const unsigned lbl = __umulhi(col, 0xCCCCCCCDu) >> 2;   // col/5
            const bool valid = col < NPROTO;
            #pragma unroll
            for (int mi = 0; mi < 4; ++mi)
                #pragma unroll
                for (int r = 0; r < 4; ++r) {
                    const float v = acc[mi][ni][r];
                    const bool same = (lbl == (unsigned)yv[mi * 4 + r]);
                    const int i = mi * 4 + r;
                    pmv[i] = same ? fmaxf(pmv[i], v) : pmv[i];
                    nmv[i] = (!same && valid) ? fmaxf(nmv[i], v) : nmv[i];
                }
        }
    }

    // reduce over the 16 col-lanes (lm) in-register
    #pragma unroll
    for (int i = 0; i < 16; ++i) {
        #pragma unroll
        for (int off = 1; off < 16; off <<= 1) {
            pmv[i] = fmaxf(pmv[i], __shfl_xor(pmv[i], off));
            nmv[i] = fmaxf(nmv[i], __shfl_xor(nmv[i], off));
        }
    }
    if (lm == 0) {
        #pragma unroll
        for (int mi = 0; mi < 4; ++mi)
            #pragma unroll
            for (int r = 0; r < 4; ++r) {
                redP[w][mi * 16 + lk * 4 + r] = pmv[mi * 4 + r];
                redN[w][mi * 16 + lk * 4 + r] = nmv[mi * 4 + r];
            }
    }
    __syncthreads();
    // final cross-wave merge + direct output write (no atomics)
    if (t < 64) {
        float p = redP[0][t], n = redN[0][t];
        #pragma unroll
        for (int ww = 1; ww < 16; ++ww) {
            p = fmaxf(p, redP[ww][t]);
            n = fmaxf(n, redN[ww][t]);
        }
        out[rowbase + t] = p;
        out[BATCH + rowbase + t] = n;
    }
}

extern "C" void kernel_launch(void* const* d_in, const int* in_sizes, int n_in,
                              void* d_out, int out_size, void* d_ws, size_t ws_size,
                              hipStream_t stream) {
    const float* z = (const float*)d_in[0];
    const int*   y = (const int*)d_in[1];
    const float* P = (const float*)d_in[2];

    // ws: zb 33.5MB | pbf 10.5MB
    unsigned short* zb = (unsigned short*)d_ws;
    unsigned short* pbf = zb + (size_t)BATCH * D;
    float* out = (float*)d_out;

    k_prep<<<BATCH + NPROTO_PAD, 256, 0, stream>>>(z, P, zb, pbf);
    k_gemm<<<BATCH / BM, 1024, 0, stream>>>(zb, pbf, y, out);
}

// Round 10
// 180.855 us; speedup vs baseline: 1.5401x; 1.0417x over previous
//
#include <hip/hip_runtime.h>
#include <hip/hip_bf16.h>
#include <stdint.h>

#define BATCH 16384
#define D 1024
#define NCLS 1000
#define NPROTO 5000
#define NPROTO_PAD 5120
#define BM 64                 // rows per block (one block per CU)
#define NCH 5                 // N chunks of 1024 cols (16 waves x 64)
#define NKT 32                // K tiles of 32
#define KSTRIDE (320 * 64 * 8)   // pbf elems per kt

typedef float f32x4 __attribute__((ext_vector_type(4)));
typedef __bf16 bf16x8 __attribute__((ext_vector_type(8)));

__device__ __forceinline__ unsigned short f2bf(float x) {
    unsigned u = __float_as_uint(x);
    u += 0x7FFFu + ((u >> 16) & 1u);   // RNE
    return (unsigned short)(u >> 16);
}

// ---------- normalize rows of z and P to bf16 ----------
// zb:  [BATCH][1024] row-major
// pbf: [kt 0..31][grp 0..319][lane 0..63][8]  (lane = (col&15) + 16*lk)
//      -> a wave's B-fragment load is contiguous 1KB
__global__ __launch_bounds__(256) void k_prep(
        const float* __restrict__ z, const float* __restrict__ P,
        unsigned short* __restrict__ zb, unsigned short* __restrict__ pbf) {
    const int b = blockIdx.x;
    const int t = threadIdx.x;
    const int e0 = 4 * t;
    const float* src = nullptr;
    unsigned short* dst;
    if (b < BATCH) {
        src = z + (size_t)b * D;
        dst = zb + (size_t)b * D + e0;
    } else {
        const int r = b - BATCH;
        const int kt = e0 >> 5;
        const int lk = (e0 >> 3) & 3;
        const int ke = e0 & 7;
        dst = pbf + (((size_t)kt * 320 + (r >> 4)) * 64 + (r & 15) + 16 * lk) * 8 + ke;
        if (r < NPROTO) src = P + (size_t)r * D;
    }
    if (src == nullptr) {                 // padded proto row -> zeros
        *(ushort4*)dst = make_ushort4(0, 0, 0, 0);
        return;
    }
    float4 v = ((const float4*)src)[t];
    float ss = v.x * v.x + v.y * v.y + v.z * v.z + v.w * v.w;
    #pragma unroll
    for (int o = 32; o >= 1; o >>= 1) ss += __shfl_xor(ss, o);
    __shared__ float red[4];
    const int wave = t >> 6;
    if ((t & 63) == 0) red[wave] = ss;
    __syncthreads();
    const float s = red[0] + red[1] + red[2] + red[3];
    const float inv = 1.0f / fmaxf(sqrtf(s), 1e-12f);
    ushort4 o4;
    o4.x = f2bf(v.x * inv); o4.y = f2bf(v.y * inv);
    o4.z = f2bf(v.z * inv); o4.w = f2bf(v.w * inv);
    *(ushort4*)dst = o4;
}

#define MM(A, B, C) __builtin_amdgcn_mfma_f32_16x16x32_bf16(A, B, C, 0, 0, 0)

// ---------- persistent-tile GEMM: A resident in LDS, B streamed to regs ----
// 256 blocks x 1024 threads (16 waves = 4/SIMD). Wave tile 64x64 (acc[4][4]):
// 2x FLOP per LDS byte vs R9; MFMA is the critical pipe.
__global__ __launch_bounds__(1024, 4) void k_gemm(
        const unsigned short* __restrict__ zb,
        const unsigned short* __restrict__ pbf,
        const int* __restrict__ y,
        float* __restrict__ out) {
    // A fragment-packed: LA[kt][row-group 0..3][lane][8]
    __shared__ __align__(16) unsigned short LA[NKT][4][64][8];   // 128 KiB
    __shared__ float redP[16][64];
    __shared__ float redN[16][64];

    const int t = threadIdx.x;
    const int w = t >> 6;                // wave 0..15 = N-slice
    const int lane = t & 63;
    const int lm = lane & 15, lk = lane >> 4;
    const int rowbase = blockIdx.x * BM;

    // ---- one-time: stage this block's 64x1024 A tile, fragment-packed ----
    {
        const int ktw = lane >> 1;
        const int lk0 = (lane & 1) * 2;
        #pragma unroll
        for (int j = 0; j < 4; ++j) {
            const int r = w * 4 + j;
            const unsigned short* gp = zb + (size_t)(rowbase + r) * D + lane * 16;
            const bf16x8 v0 = *(const bf16x8*)gp;
            const bf16x8 v1 = *(const bf16x8*)(gp + 8);
            *(bf16x8*)&LA[ktw][r >> 4][(r & 15) + 16 * lk0][0] = v0;
            *(bf16x8*)&LA[ktw][r >> 4][(r & 15) + 16 * (lk0 + 1)][0] = v1;
        }
    }
    // this lane's 16 output rows' labels
    int yv[16];
    #pragma unroll
    for (int mi = 0; mi < 4; ++mi)
        #pragma unroll
        for (int r = 0; r < 4; ++r)
            yv[mi * 4 + r] = y[rowbase + mi * 16 + lk * 4 + r];

    __syncthreads();

    float pmv[16], nmv[16];
    #pragma unroll
    for (int i = 0; i < 16; ++i) { pmv[i] = -INFINITY; nmv[i] = -INFINITY; }

    // ---- N-chunk sweep: 5 chunks x 1024 cols; wave w owns cols w*64..+64 --
    #pragma unroll 1
    for (int c = 0; c < NCH; ++c) {
        const int grp0 = c * 64 + w * 4;
        const unsigned short* pB = pbf + ((size_t)grp0 * 64 + lane) * 8;

        f32x4 acc[4][4];
        #pragma unroll
        for (int mi = 0; mi < 4; ++mi)
            #pragma unroll
            for (int ni = 0; ni < 4; ++ni) {
                f32x4 z4 = {0.0f, 0.0f, 0.0f, 0.0f};
                acc[mi][ni] = z4;
            }

        // prologue: B frags for kt 0
        bf16x8 bc0 = *(const bf16x8*)(pB);
        bf16x8 bc1 = *(const bf16x8*)(pB + 512);
        bf16x8 bc2 = *(const bf16x8*)(pB + 1024);
        bf16x8 bc3 = *(const bf16x8*)(pB + 1536);
        bf16x8 bn0, bn1, bn2, bn3;

        #pragma unroll 1
        for (int kt = 0; kt < NKT; kt += 2) {
            // prefetch kt+1 (always < NKT)
            {
                const unsigned short* q = pB + (size_t)(kt + 1) * KSTRIDE;
                bn0 = *(const bf16x8*)(q);
                bn1 = *(const bf16x8*)(q + 512);
                bn2 = *(const bf16x8*)(q + 1024);
                bn3 = *(const bf16x8*)(q + 1536);
            }
            // even K-tile: consume bc
            {
                const bf16x8 a0 = *(const bf16x8*)&LA[kt][0][lane][0];
                const bf16x8 a1 = *(const bf16x8*)&LA[kt][1][lane][0];
                const bf16x8 a2 = *(const bf16x8*)&LA[kt][2][lane][0];
                const bf16x8 a3 = *(const bf16x8*)&LA[kt][3][lane][0];
                acc[0][0] = MM(a0, bc0, acc[0][0]);
                acc[0][1] = MM(a0, bc1, acc[0][1]);
                acc[0][2] = MM(a0, bc2, acc[0][2]);
                acc[0][3] = MM(a0, bc3, acc[0][3]);
                acc[1][0] = MM(a1, bc0, acc[1][0]);
                acc[1][1] = MM(a1, bc1, acc[1][1]);
                acc[1][2] = MM(a1, bc2, acc[1][2]);
                acc[1][3] = MM(a1, bc3, acc[1][3]);
                acc[2][0] = MM(a2, bc0, acc[2][0]);
                acc[2][1] = MM(a2, bc1, acc[2][1]);
                acc[2][2] = MM(a2, bc2, acc[2][2]);
                acc[2][3] = MM(a2, bc3, acc[2][3]);
                acc[3][0] = MM(a3, bc0, acc[3][0]);
                acc[3][1] = MM(a3, bc1, acc[3][1]);
                acc[3][2] = MM(a3, bc2, acc[3][2]);
                acc[3][3] = MM(a3, bc3, acc[3][3]);
            }
            // prefetch kt+2 into bc (clamp at tail; redundant load is benign)
            {
                const int ktn = (kt + 2 < NKT) ? kt + 2 : NKT - 1;
                const unsigned short* q = pB + (size_t)ktn * KSTRIDE;
                bc0 = *(const bf16x8*)(q);
                bc1 = *(const bf16x8*)(q + 512);
                bc2 = *(const bf16x8*)(q + 1024);
                bc3 = *(const bf16x8*)(q + 1536);
            }
            // odd K-tile: consume bn
            {
                const bf16x8 a0 = *(const bf16x8*)&LA[kt + 1][0][lane][0];
                const bf16x8 a1 = *(const bf16x8*)&LA[kt + 1][1][lane][0];
                const bf16x8 a2 = *(const bf16x8*)&LA[kt + 1][2][lane][0];
                const bf16x8 a3 = *(const bf16x8*)&LA[kt + 1][3][lane][0];
                acc[0][0] = MM(a0, bn0, acc[0][0]);
                acc[0][1] = MM(a0, bn1, acc[0][1]);
                acc[0][2] = MM(a0, bn2, acc[0][2]);
                acc[0][3] = MM(a0, bn3, acc[0][3]);
                acc[1][0] = MM(a1, bn0, acc[1][0]);
                acc[1][1] = MM(a1, bn1, acc[1][1]);
                acc[1][2] = MM(a1, bn2, acc[1][2]);
                acc[1][3] = MM(a1, bn3, acc[1][3]);
                acc[2][0] = MM(a2, bn0, acc[2][0]);
                acc[2][1] = MM(a2, bn1, acc[2][1]);
                acc[2][2] = MM(a2, bn2, acc[2][2]);
                acc[2][3] = MM(a2, bn3, acc[2][3]);
                acc[3][0] = MM(a3, bn0, acc[3][0]);
                acc[3][1] = MM(a3, bn1, acc[3][1]);
                acc[3][2] = MM(a3, bn2, acc[3][2]);
                acc[3][3] = MM(a3, bn3, acc[3][3]);
            }
        }

        // merge chunk into running pos/neg maxes (register-only)
        #pragma unroll
        for (int ni = 0; ni < 4; ++ni) {
            const unsigned col = (unsigned)(c * 1024 + w * 64 + ni * 16 + lm);
            const unsigned lbl = __umulhi(col, 0xCCCCCCCDu) >> 2;   // col/5
            const bool valid = col < NPROTO;
            #pragma unroll
            for (int mi = 0; mi < 4; ++mi)
                #pragma unroll
                for (int r = 0; r < 4; ++r) {
                    const float v = acc[mi][ni][r];
                    const bool same = (lbl == (unsigned)yv[mi * 4 + r]);
                    const int i = mi * 4 + r;
                    pmv[i] = same ? fmaxf(pmv[i], v) : pmv[i];
                    nmv[i] = (!same && valid) ? fmaxf(nmv[i], v) : nmv[i];
                }
        }
    }

    // reduce over the 16 col-lanes (lm) in-register
    #pragma unroll
    for (int i = 0; i < 16; ++i) {
        #pragma unroll
        for (int off = 1; off < 16; off <<= 1) {
            pmv[i] = fmaxf(pmv[i], __shfl_xor(pmv[i], off));
            nmv[i] = fmaxf(nmv[i], __shfl_xor(nmv[i], off));
        }
    }
    if (lm == 0) {
        #pragma unroll
        for (int mi = 0; mi < 4; ++mi)
            #pragma unroll
            for (int r = 0; r < 4; ++r) {
                redP[w][mi * 16 + lk * 4 + r] = pmv[mi * 4 + r];
                redN[w][mi * 16 + lk * 4 + r] = nmv[mi * 4 + r];
            }
    }
    __syncthreads();
    // final cross-wave merge + direct output write (no atomics)
    if (t < 64) {
        float p = redP[0][t], n = redN[0][t];
        #pragma unroll
        for (int ww = 1; ww < 16; ++ww) {
            p = fmaxf(p, redP[ww][t]);
            n = fmaxf(n, redN[ww][t]);
        }
        out[rowbase + t] = p;
        out[BATCH + rowbase + t] = n;
    }
}

extern "C" void kernel_launch(void* const* d_in, const int* in_sizes, int n_in,
                              void* d_out, int out_size, void* d_ws, size_t ws_size,
                              hipStream_t stream) {
    const float* z = (const float*)d_in[0];
    const int*   y = (const int*)d_in[1];
    const float* P = (const float*)d_in[2];

    // ws: zb 33.5MB | pbf 10.5MB
    unsigned short* zb = (unsigned short*)d_ws;
    unsigned short* pbf = zb + (size_t)BATCH * D;
    float* out = (float*)d_out;

    k_prep<<<BATCH + NPROTO_PAD, 256, 0, stream>>>(z, P, zb, pbf);
    k_gemm<<<BATCH / BM, 1024, 0, stream>>>(zb, pbf, y, out);
}